// Round 1
// baseline (2486.409 us; speedup 1.0000x reference)
//
#include <hip/hip_runtime.h>
#include <hip/hip_bf16.h>
#include <math.h>

// Problem constants (from reference setup_inputs)
#define N_TOK 1024
#define TOPK  2
#define NEXP  16
#define HID   1024   // H
#define DIM   2048   // D
#define RANK  16
#define NPAIR (N_TOK * TOPK)
#define MOE_SCALE 0.25f

#define TM 64   // M tile (tokens per block)
#define BK 32   // K chunk per MFMA step

typedef __attribute__((ext_vector_type(8))) short short8;
typedef __attribute__((ext_vector_type(4))) float floatx4;

static __device__ __forceinline__ unsigned short f2bf(float f) {
    union { float f; unsigned int u; } v; v.f = f;
    unsigned int u = v.u;
    u += 0x7fffu + ((u >> 16) & 1u);   // RNE
    return (unsigned short)(u >> 16);
}

static __device__ __forceinline__ float bf2f(unsigned short s) {
    union { unsigned int u; float f; } v; v.u = ((unsigned int)s) << 16;
    return v.f;
}

// ---------------------------------------------------------------------------
// Kernel A: routing — sort pair indices by expert. One block.
// ---------------------------------------------------------------------------
__global__ void k_routing(const int* __restrict__ ids,
                          int* __restrict__ offs,      // [NEXP+1]
                          int* __restrict__ sorted) {  // [NPAIR]
    __shared__ int s_cnt[NEXP];
    __shared__ int s_off[NEXP + 1];
    int tid = threadIdx.x;
    if (tid < NEXP) s_cnt[tid] = 0;
    __syncthreads();
    for (int p = tid; p < NPAIR; p += blockDim.x) atomicAdd(&s_cnt[ids[p]], 1);
    __syncthreads();
    if (tid == 0) {
        int acc = 0;
        for (int e = 0; e < NEXP; ++e) { s_off[e] = acc; acc += s_cnt[e]; }
        s_off[NEXP] = acc;
    }
    __syncthreads();
    if (tid <= NEXP) offs[tid] = s_off[tid];
    if (tid < NEXP) s_cnt[tid] = s_off[tid];   // reuse as cursor
    __syncthreads();
    for (int p = tid; p < NPAIR; p += blockDim.x) {
        int e = ids[p];
        int slot = atomicAdd(&s_cnt[e], 1);
        sorted[slot] = p;
    }
}

// ---------------------------------------------------------------------------
// Kernel B: t_up[p][r] = SCALE * dot(x[n], up_a[e][r]).  One wave per pair.
// ---------------------------------------------------------------------------
__global__ void k_tup(const float* __restrict__ x, const int* __restrict__ ids,
                      const float* __restrict__ up_a, float* __restrict__ t_up) {
    int p = blockIdx.x;
    int lane = threadIdx.x;             // 64
    int n = p / TOPK;
    int e = ids[p];
    const float* xr = x + (size_t)n * DIM;
    const float* ar = up_a + (size_t)e * RANK * DIM;
    for (int r = 0; r < RANK; ++r) {
        const float* a = ar + (size_t)r * DIM;
        float s = 0.f;
        for (int d = lane; d < DIM; d += 64) s += xr[d] * a[d];
        for (int m = 32; m; m >>= 1) s += __shfl_xor(s, m, 64);
        if (lane == 0) t_up[(size_t)p * RANK + r] = MOE_SCALE * s;
    }
}

// ---------------------------------------------------------------------------
// Kernel C: grouped up-GEMM + LoRA epilogue + gelu*mul -> act (bf16, by slot)
// Block: 256 thr (4 waves). Tile: 64 tokens x 64 h-cols (both halves of 2H).
// ---------------------------------------------------------------------------
__global__ __launch_bounds__(256) void k_up(
        const float* __restrict__ x, const int* __restrict__ ids,
        const float* __restrict__ w_up, const float* __restrict__ up_b,
        const float* __restrict__ t_up,
        const int* __restrict__ offs, const int* __restrict__ sorted,
        unsigned short* __restrict__ act) {
    int e  = blockIdx.x >> 5;
    int mt = blockIdx.x & 31;
    int off = offs[e], cnt = offs[e + 1] - off;
    if (mt * TM >= cnt) return;
    int hb = blockIdx.y * 64;

    __shared__ unsigned short sA[TM][BK];
    __shared__ unsigned short sB1[64][BK];
    __shared__ unsigned short sB2[64][BK];

    int tid = threadIdx.x;

    // A staging: 64 rows x 32 cols, 8 floats/thread
    int arow = tid >> 2;
    int acol = (tid & 3) * 8;
    const float* xrow = nullptr;
    {
        int gr = mt * TM + arow;
        if (gr < cnt) {
            int p = sorted[off + gr];
            xrow = x + (size_t)(p >> 1) * DIM;   // n = p / TOPK (TOPK==2)
        }
    }
    // B staging: 128 rows (64 per half) x 32 cols, 16 floats/thread
    int brow = tid >> 1;
    int bcol = (tid & 1) * 16;
    int wrow = (brow < 64) ? (hb + brow) : (HID + hb + (brow - 64));
    const float* wptr = w_up + ((size_t)e * 2 * HID + wrow) * DIM;

    int lane = tid & 63, wv = tid >> 6;
    int lm = lane & 15, lq = lane >> 4;

    floatx4 acc1[4], acc2[4];
    floatx4 zero = {0.f, 0.f, 0.f, 0.f};
    for (int i = 0; i < 4; ++i) { acc1[i] = zero; acc2[i] = zero; }

    for (int k0 = 0; k0 < DIM; k0 += BK) {
        // stage A
        short8 av;
        if (xrow) {
            float4 v0 = *(const float4*)(xrow + k0 + acol);
            float4 v1 = *(const float4*)(xrow + k0 + acol + 4);
            av[0] = (short)f2bf(v0.x); av[1] = (short)f2bf(v0.y);
            av[2] = (short)f2bf(v0.z); av[3] = (short)f2bf(v0.w);
            av[4] = (short)f2bf(v1.x); av[5] = (short)f2bf(v1.y);
            av[6] = (short)f2bf(v1.z); av[7] = (short)f2bf(v1.w);
        } else {
            for (int i = 0; i < 8; ++i) av[i] = 0;
        }
        *(short8*)(&sA[arow][acol]) = av;
        // stage B (16 floats)
        {
            float4 b0 = *(const float4*)(wptr + k0 + bcol);
            float4 b1 = *(const float4*)(wptr + k0 + bcol + 4);
            float4 b2 = *(const float4*)(wptr + k0 + bcol + 8);
            float4 b3 = *(const float4*)(wptr + k0 + bcol + 12);
            unsigned short* dst = (brow < 64) ? &sB1[brow][bcol] : &sB2[brow - 64][bcol];
            short8 w0, w1;
            w0[0] = (short)f2bf(b0.x); w0[1] = (short)f2bf(b0.y);
            w0[2] = (short)f2bf(b0.z); w0[3] = (short)f2bf(b0.w);
            w0[4] = (short)f2bf(b1.x); w0[5] = (short)f2bf(b1.y);
            w0[6] = (short)f2bf(b1.z); w0[7] = (short)f2bf(b1.w);
            w1[0] = (short)f2bf(b2.x); w1[1] = (short)f2bf(b2.y);
            w1[2] = (short)f2bf(b2.z); w1[3] = (short)f2bf(b2.w);
            w1[4] = (short)f2bf(b3.x); w1[5] = (short)f2bf(b3.y);
            w1[6] = (short)f2bf(b3.z); w1[7] = (short)f2bf(b3.w);
            *(short8*)(dst) = w0;
            *(short8*)(dst + 8) = w1;
        }
        __syncthreads();
        short8 af = *(const short8*)(&sA[wv * 16 + lm][lq * 8]);
#pragma unroll
        for (int nt = 0; nt < 4; ++nt) {
            short8 bf1 = *(const short8*)(&sB1[nt * 16 + lm][lq * 8]);
            acc1[nt] = __builtin_amdgcn_mfma_f32_16x16x32_bf16(af, bf1, acc1[nt], 0, 0, 0);
            short8 bf2 = *(const short8*)(&sB2[nt * 16 + lm][lq * 8]);
            acc2[nt] = __builtin_amdgcn_mfma_f32_16x16x32_bf16(af, bf2, acc2[nt], 0, 0, 0);
        }
        __syncthreads();
    }

    // epilogue: LoRA rank-16 add + erf-gelu * mul, write act (bf16) by slot
    const float* tB = up_b + (size_t)e * 2 * HID * RANK;
#pragma unroll
    for (int nt = 0; nt < 4; ++nt) {
        int h = hb + nt * 16 + lm;
        const float* b1 = tB + (size_t)h * RANK;
        const float* b2 = tB + (size_t)(h + HID) * RANK;
        float r1[RANK], r2[RANK];
#pragma unroll
        for (int i = 0; i < RANK; ++i) { r1[i] = b1[i]; r2[i] = b2[i]; }
#pragma unroll
        for (int r = 0; r < 4; ++r) {
            int row = wv * 16 + lq * 4 + r;
            int g = mt * TM + row;
            if (g < cnt) {
                int p = sorted[off + g];
                const float* tv = t_up + (size_t)p * RANK;
                float s1 = acc1[nt][r], s2 = acc2[nt][r];
#pragma unroll
                for (int i = 0; i < RANK; ++i) { s1 += tv[i] * r1[i]; s2 += tv[i] * r2[i]; }
                float gl = 0.5f * s1 * (1.f + erff(s1 * 0.70710678118654752f));
                act[(size_t)(off + g) * HID + h] = f2bf(gl * s2);
            }
        }
    }
}

// ---------------------------------------------------------------------------
// Kernel D: t2[slot][r] = SCALE * dot(act[slot], down_a[e][r]). One wave/slot.
// ---------------------------------------------------------------------------
__global__ void k_t2(const unsigned short* __restrict__ act,
                     const int* __restrict__ ids, const int* __restrict__ sorted,
                     const float* __restrict__ down_a, float* __restrict__ t2) {
    int s = blockIdx.x;
    int lane = threadIdx.x;
    int p = sorted[s];
    int e = ids[p];
    const unsigned short* ar = act + (size_t)s * HID;
    const float* da = down_a + (size_t)e * RANK * HID;
    float av[16];
#pragma unroll
    for (int i = 0; i < 16; ++i) av[i] = bf2f(ar[lane + i * 64]);
    for (int r = 0; r < RANK; ++r) {
        const float* a = da + (size_t)r * HID;
        float sum = 0.f;
#pragma unroll
        for (int i = 0; i < 16; ++i) sum += av[i] * a[lane + i * 64];
        for (int m = 32; m; m >>= 1) sum += __shfl_xor(sum, m, 64);
        if (lane == 0) t2[(size_t)s * RANK + r] = MOE_SCALE * sum;
    }
}

// ---------------------------------------------------------------------------
// Kernel E: grouped down-GEMM + LoRA + topk-weight + scatter-add into out.
// ---------------------------------------------------------------------------
__global__ __launch_bounds__(256) void k_down(
        const unsigned short* __restrict__ act,
        const int* __restrict__ ids, const float* __restrict__ tw,
        const float* __restrict__ w_down, const float* __restrict__ down_b,
        const float* __restrict__ t2,
        const int* __restrict__ offs, const int* __restrict__ sorted,
        float* __restrict__ out) {
    int e  = blockIdx.x >> 5;
    int mt = blockIdx.x & 31;
    int off = offs[e], cnt = offs[e + 1] - off;
    if (mt * TM >= cnt) return;
    int db = blockIdx.y * 64;

    __shared__ unsigned short sA[TM][BK];
    __shared__ unsigned short sB[64][BK];

    int tid = threadIdx.x;
    int arow = tid >> 2;
    int acol = (tid & 3) * 8;
    const unsigned short* arp = nullptr;
    {
        int gr = mt * TM + arow;
        if (gr < cnt) arp = act + (size_t)(off + gr) * HID;
    }
    int brow = tid >> 2;
    int bcol = (tid & 3) * 8;
    const float* wptr = w_down + ((size_t)e * DIM + (db + brow)) * HID;

    int lane = tid & 63, wv = tid >> 6;
    int lm = lane & 15, lq = lane >> 4;

    floatx4 acc[4];
    floatx4 zero = {0.f, 0.f, 0.f, 0.f};
    for (int i = 0; i < 4; ++i) acc[i] = zero;

    for (int k0 = 0; k0 < HID; k0 += BK) {
        if (arp) {
            *(short8*)(&sA[arow][acol]) = *(const short8*)(arp + k0 + acol);
        } else {
            short8 z; for (int i = 0; i < 8; ++i) z[i] = 0;
            *(short8*)(&sA[arow][acol]) = z;
        }
        {
            float4 b0 = *(const float4*)(wptr + k0 + bcol);
            float4 b1 = *(const float4*)(wptr + k0 + bcol + 4);
            short8 w0;
            w0[0] = (short)f2bf(b0.x); w0[1] = (short)f2bf(b0.y);
            w0[2] = (short)f2bf(b0.z); w0[3] = (short)f2bf(b0.w);
            w0[4] = (short)f2bf(b1.x); w0[5] = (short)f2bf(b1.y);
            w0[6] = (short)f2bf(b1.z); w0[7] = (short)f2bf(b1.w);
            *(short8*)(&sB[brow][bcol]) = w0;
        }
        __syncthreads();
        short8 af = *(const short8*)(&sA[wv * 16 + lm][lq * 8]);
#pragma unroll
        for (int nt = 0; nt < 4; ++nt) {
            short8 bf = *(const short8*)(&sB[nt * 16 + lm][lq * 8]);
            acc[nt] = __builtin_amdgcn_mfma_f32_16x16x32_bf16(af, bf, acc[nt], 0, 0, 0);
        }
        __syncthreads();
    }

    // epilogue: + SCALE*ldown (t2 dot down_b row), * topk_weight, atomic add
#pragma unroll
    for (int nt = 0; nt < 4; ++nt) {
        int d = db + nt * 16 + lm;
        const float* rb = down_b + ((size_t)e * DIM + d) * RANK;
        float rbv[RANK];
#pragma unroll
        for (int i = 0; i < RANK; ++i) rbv[i] = rb[i];
#pragma unroll
        for (int r = 0; r < 4; ++r) {
            int row = wv * 16 + lq * 4 + r;
            int g = mt * TM + row;
            if (g < cnt) {
                int slot = off + g;
                int p = sorted[slot];
                const float* tv = t2 + (size_t)slot * RANK;
                float val = acc[nt][r];
#pragma unroll
                for (int i = 0; i < RANK; ++i) val += tv[i] * rbv[i];
                float w = tw[p];
                atomicAdd(&out[(size_t)(p >> 1) * DIM + d], val * w);
            }
        }
    }
}

// ---------------------------------------------------------------------------
extern "C" void kernel_launch(void* const* d_in, const int* in_sizes, int n_in,
                              void* d_out, int out_size, void* d_ws, size_t ws_size,
                              hipStream_t stream) {
    const float* x      = (const float*)d_in[0];
    const float* tw     = (const float*)d_in[1];
    const int*   ids    = (const int*)d_in[2];
    const float* w_up   = (const float*)d_in[3];
    const float* w_down = (const float*)d_in[4];
    const float* up_a   = (const float*)d_in[5];
    const float* up_b   = (const float*)d_in[6];
    const float* down_a = (const float*)d_in[7];
    const float* down_b = (const float*)d_in[8];
    float* out = (float*)d_out;

    char* ws = (char*)d_ws;
    int*   offs   = (int*)ws;                              // 17 ints
    int*   sorted = (int*)(ws + 1024);                     // 2048 ints
    float* t_up   = (float*)(ws + 16384);                  // 2048*16 f32
    float* t2     = (float*)(ws + 16384 + 131072);         // 2048*16 f32
    unsigned short* act = (unsigned short*)(ws + 16384 + 262144);  // 2048*1024 bf16

    hipMemsetAsync(d_out, 0, (size_t)out_size * sizeof(float), stream);

    k_routing<<<1, 256, 0, stream>>>(ids, offs, sorted);
    k_tup<<<NPAIR, 64, 0, stream>>>(x, ids, up_a, t_up);

    dim3 gup(NEXP * 32, HID / 64);
    k_up<<<gup, 256, 0, stream>>>(x, ids, w_up, up_b, t_up, offs, sorted, act);

    k_t2<<<NPAIR, 64, 0, stream>>>(act, ids, sorted, down_a, t2);

    dim3 gdn(NEXP * 32, DIM / 64);
    k_down<<<gdn, 256, 0, stream>>>(act, ids, tw, w_down, down_b, t2, offs, sorted, out);
}

// Round 2
// 1850.633 us; speedup vs baseline: 1.3435x; 1.3435x over previous
//
#include <hip/hip_runtime.h>
#include <hip/hip_bf16.h>
#include <math.h>

// Problem constants
#define N_TOK 1024
#define TOPK  2
#define NEXP  16
#define HID   1024   // H
#define DIM   2048   // D
#define RANK  16
#define NPAIR (N_TOK * TOPK)
#define MOE_SCALE 0.25f

typedef __attribute__((ext_vector_type(8))) short short8;
typedef __attribute__((ext_vector_type(4))) float floatx4;

static __device__ __forceinline__ unsigned short f2bf(float f) {
    union { float f; unsigned int u; } v; v.f = f;
    unsigned int u = v.u;
    u += 0x7fffu + ((u >> 16) & 1u);   // RNE
    return (unsigned short)(u >> 16);
}

static __device__ __forceinline__ float bf2f(unsigned short s) {
    union { unsigned int u; float f; } v; v.u = ((unsigned int)s) << 16;
    return v.f;
}

// async global->LDS 16B per lane. LDS operand must be wave-uniform.
static __device__ __forceinline__ void gload16(const unsigned short* g, unsigned short* l) {
    __builtin_amdgcn_global_load_lds(
        (const __attribute__((address_space(1))) unsigned int*)g,
        (__attribute__((address_space(3))) unsigned int*)l, 16, 0, 0);
}

// ---------------------------------------------------------------------------
// Kernel: routing — sort pair indices by expert. One block.
// ---------------------------------------------------------------------------
__global__ void k_routing(const int* __restrict__ ids,
                          int* __restrict__ offs,      // [NEXP+1]
                          int* __restrict__ sorted) {  // [NPAIR]
    __shared__ int s_cnt[NEXP];
    __shared__ int s_off[NEXP + 1];
    int tid = threadIdx.x;
    if (tid < NEXP) s_cnt[tid] = 0;
    __syncthreads();
    for (int p = tid; p < NPAIR; p += blockDim.x) atomicAdd(&s_cnt[ids[p]], 1);
    __syncthreads();
    if (tid == 0) {
        int acc = 0;
        for (int e = 0; e < NEXP; ++e) { s_off[e] = acc; acc += s_cnt[e]; }
        s_off[NEXP] = acc;
    }
    __syncthreads();
    if (tid <= NEXP) offs[tid] = s_off[tid];
    if (tid < NEXP) s_cnt[tid] = s_off[tid];
    __syncthreads();
    for (int p = tid; p < NPAIR; p += blockDim.x) {
        int e = ids[p];
        int slot = atomicAdd(&s_cnt[e], 1);
        sorted[slot] = p;
    }
}

// ---------------------------------------------------------------------------
// Kernel: xs pack — xs[slot][d] = bf16(x[n(sorted[slot])][d])
// ---------------------------------------------------------------------------
__global__ void k_xspack(const float* __restrict__ x, const int* __restrict__ sorted,
                         unsigned short* __restrict__ xs) {
    int idx = blockIdx.x * 256 + threadIdx.x;   // NPAIR*256 threads
    int slot = idx >> 8, c8 = idx & 255;
    int p = sorted[slot];
    const float* src = x + (size_t)(p >> 1) * DIM + c8 * 8;
    float4 v0 = *(const float4*)src;
    float4 v1 = *(const float4*)(src + 4);
    short8 o;
    o[0] = (short)f2bf(v0.x); o[1] = (short)f2bf(v0.y);
    o[2] = (short)f2bf(v0.z); o[3] = (short)f2bf(v0.w);
    o[4] = (short)f2bf(v1.x); o[5] = (short)f2bf(v1.y);
    o[6] = (short)f2bf(v1.z); o[7] = (short)f2bf(v1.w);
    *(short8*)(xs + (size_t)slot * DIM + c8 * 8) = o;
}

// ---------------------------------------------------------------------------
// Kernel: pack w_up fp32 -> bf16 tiles pUp[e][nt:16][kc:32][r128][c64] with
// XOR-8 16B-chunk swizzle. r<64: gate row h=nt*64+r; r>=64: mul row (+HID).
// ---------------------------------------------------------------------------
__global__ void k_packup(const float* __restrict__ w, unsigned short* __restrict__ pk) {
    const int total = NEXP * 2048 * 256;   // 8,388,608 chunks of 8 floats
    for (int idx = blockIdx.x * 256 + threadIdx.x; idx < total; idx += gridDim.x * 256) {
        int e   = idx >> 19;
        int rem = idx & ((1 << 19) - 1);
        int row = rem >> 8;          // [0,2048) of w_up[e]
        int c8  = rem & 255;         // 8-float chunk in row
        const float* src = w + ((size_t)e * 2048 + row) * 2048 + c8 * 8;
        float4 v0 = *(const float4*)src;
        float4 v1 = *(const float4*)(src + 4);
        short8 o;
        o[0] = (short)f2bf(v0.x); o[1] = (short)f2bf(v0.y);
        o[2] = (short)f2bf(v0.z); o[3] = (short)f2bf(v0.w);
        o[4] = (short)f2bf(v1.x); o[5] = (short)f2bf(v1.y);
        o[6] = (short)f2bf(v1.z); o[7] = (short)f2bf(v1.w);
        int hf   = row >> 10;                 // 0 = gate half, 1 = mul half
        int h    = row & 1023;
        int nt   = h >> 6;
        int r128 = (h & 63) + hf * 64;
        int kc   = c8 >> 3;
        int cc   = (c8 & 7) ^ (r128 & 7);
        size_t dst = ((((size_t)(e * 16 + nt) * 32 + kc) * 128 + r128) * 8 + cc) * 8;
        *(short8*)(pk + dst) = o;
    }
}

// ---------------------------------------------------------------------------
// Kernel: pack w_down fp32 -> bf16 tiles pDn[e][nt:16][kc:16][r128][c64]
// ---------------------------------------------------------------------------
__global__ void k_packdn(const float* __restrict__ w, unsigned short* __restrict__ pk) {
    const int total = NEXP * 2048 * 128;   // 4,194,304 chunks
    for (int idx = blockIdx.x * 256 + threadIdx.x; idx < total; idx += gridDim.x * 256) {
        int e   = idx >> 18;
        int rem = idx & ((1 << 18) - 1);
        int row = rem >> 7;          // d in [0,2048)
        int c8  = rem & 127;         // chunk in 1024-col row
        const float* src = w + ((size_t)e * 2048 + row) * 1024 + c8 * 8;
        float4 v0 = *(const float4*)src;
        float4 v1 = *(const float4*)(src + 4);
        short8 o;
        o[0] = (short)f2bf(v0.x); o[1] = (short)f2bf(v0.y);
        o[2] = (short)f2bf(v0.z); o[3] = (short)f2bf(v0.w);
        o[4] = (short)f2bf(v1.x); o[5] = (short)f2bf(v1.y);
        o[6] = (short)f2bf(v1.z); o[7] = (short)f2bf(v1.w);
        int nt   = row >> 7;
        int r128 = row & 127;
        int kc   = c8 >> 3;
        int cc   = (c8 & 7) ^ (r128 & 7);
        size_t dst = ((((size_t)(e * 16 + nt) * 16 + kc) * 128 + r128) * 8 + cc) * 8;
        *(short8*)(pk + dst) = o;
    }
}

// ---------------------------------------------------------------------------
// Kernel: t_up[p][r] = SCALE * dot(x[n], up_a[e][r]).  One wave per pair.
// ---------------------------------------------------------------------------
__global__ void k_tup(const float* __restrict__ x, const int* __restrict__ ids,
                      const float* __restrict__ up_a, float* __restrict__ t_up) {
    int p = blockIdx.x;
    int lane = threadIdx.x;
    int n = p / TOPK;
    int e = ids[p];
    const float* xr = x + (size_t)n * DIM;
    const float* ar = up_a + (size_t)e * RANK * DIM;
    for (int r = 0; r < RANK; ++r) {
        const float* a = ar + (size_t)r * DIM;
        float s = 0.f;
        for (int d = lane; d < DIM; d += 64) s += xr[d] * a[d];
        for (int m = 32; m; m >>= 1) s += __shfl_xor(s, m, 64);
        if (lane == 0) t_up[(size_t)p * RANK + r] = MOE_SCALE * s;
    }
}

// ---------------------------------------------------------------------------
// Kernel: up-GEMM. Block = (expert, m-tile 128) x (n-tile: 64 h-pairs = 128
// packed rows). K-loop kc over 32 chunks of 64. B via global_load_lds from
// packed tiles; A staged from xs with swizzle. Epilogue: LoRA + gelu*mul.
// ---------------------------------------------------------------------------
__global__ __launch_bounds__(256) void k_up(
        const unsigned short* __restrict__ xs, const unsigned short* __restrict__ pUp,
        const float* __restrict__ up_b, const float* __restrict__ t_up,
        const int* __restrict__ offs, const int* __restrict__ sorted,
        unsigned short* __restrict__ act) {
    int e  = blockIdx.x >> 4;
    int mt = blockIdx.x & 15;
    int nt = blockIdx.y;
    int off = offs[e], cnt = offs[e + 1] - off;
    if (mt * 128 >= cnt) return;

    __shared__ unsigned short sA[128 * 64];   // 16 KB, swizzled
    __shared__ unsigned short sB[128 * 64];   // 16 KB, swizzled (from pack)

    int tid = threadIdx.x, lane = tid & 63, wv = tid >> 6;
    int lm = lane & 15, lq = lane >> 4;

    // A staging: thread -> row tid>>1, 4 chunks of 16B
    int ar = tid >> 1;
    int acb = (tid & 1) * 4;
    const unsigned short* axp = nullptr;
    {
        int g = mt * 128 + ar;
        if (g < cnt) axp = xs + (size_t)(off + g) * DIM;
    }
    const unsigned short* bsrc = pUp + (size_t)(e * 16 + nt) * 32 * 8192;

    floatx4 acc[2][8];
    floatx4 zero = {0.f, 0.f, 0.f, 0.f};
#pragma unroll
    for (int i = 0; i < 2; ++i)
#pragma unroll
        for (int j = 0; j < 8; ++j) acc[i][j] = zero;

    for (int kc = 0; kc < 32; ++kc) {
        const unsigned short* bk = bsrc + kc * 8192;
#pragma unroll
        for (int j = 0; j < 4; ++j) {
            int ch = wv * 4 + j;                       // 1KB chunk id (wave-uniform)
            gload16(bk + ch * 512 + lane * 8, (unsigned short*)sB + ch * 512);
        }
        if (axp) {
            const unsigned short* ap = axp + kc * 64;
#pragma unroll
            for (int i = 0; i < 4; ++i) {
                int c8 = acb + i;
                short8 v = *(const short8*)(ap + c8 * 8);
                *(short8*)(sA + ar * 64 + ((c8 ^ (ar & 7)) * 8)) = v;
            }
        }
        __syncthreads();
#pragma unroll
        for (int kk = 0; kk < 2; ++kk) {
            short8 af0, af1;
            {
                int r0 = (wv * 2) * 16 + lm;
                int r1 = (wv * 2 + 1) * 16 + lm;
                af0 = *(const short8*)(sA + r0 * 64 + (((kk * 4 + lq) ^ (r0 & 7)) * 8));
                af1 = *(const short8*)(sA + r1 * 64 + (((kk * 4 + lq) ^ (r1 & 7)) * 8));
            }
#pragma unroll
            for (int n2 = 0; n2 < 8; ++n2) {
                int r = n2 * 16 + lm;
                short8 bf = *(const short8*)(sB + r * 64 + (((kk * 4 + lq) ^ (r & 7)) * 8));
                acc[0][n2] = __builtin_amdgcn_mfma_f32_16x16x32_bf16(af0, bf, acc[0][n2], 0, 0, 0);
                acc[1][n2] = __builtin_amdgcn_mfma_f32_16x16x32_bf16(af1, bf, acc[1][n2], 0, 0, 0);
            }
        }
        __syncthreads();
    }

    // epilogue: LoRA rank-16 + erf-gelu * mul -> act[slot][h]
    const float* upb = up_b + (size_t)e * 2 * HID * RANK;
#pragma unroll
    for (int n2 = 0; n2 < 4; ++n2) {
        int h = nt * 64 + n2 * 16 + lm;
        const float* b1 = upb + (size_t)h * RANK;
        const float* b2 = upb + (size_t)(h + HID) * RANK;
        float r1[RANK], r2[RANK];
#pragma unroll
        for (int i = 0; i < RANK; ++i) { r1[i] = b1[i]; r2[i] = b2[i]; }
#pragma unroll
        for (int i = 0; i < 2; ++i) {
#pragma unroll
            for (int r = 0; r < 4; ++r) {
                int g = mt * 128 + (wv * 2 + i) * 16 + lq * 4 + r;
                if (g < cnt) {
                    int slot = off + g;
                    int p = sorted[slot];
                    const float* tv = t_up + (size_t)p * RANK;
                    float s1 = acc[i][n2][r], s2 = acc[i][n2 + 4][r];
#pragma unroll
                    for (int j = 0; j < RANK; ++j) { s1 += tv[j] * r1[j]; s2 += tv[j] * r2[j]; }
                    float gl = 0.5f * s1 * (1.f + erff(s1 * 0.70710678118654752f));
                    act[(size_t)slot * HID + h] = f2bf(gl * s2);
                }
            }
        }
    }
}

// ---------------------------------------------------------------------------
// Kernel: t2[slot][r] = SCALE * dot(act[slot], down_a[e][r]). One wave/slot.
// ---------------------------------------------------------------------------
__global__ void k_t2(const unsigned short* __restrict__ act,
                     const int* __restrict__ ids, const int* __restrict__ sorted,
                     const float* __restrict__ down_a, float* __restrict__ t2) {
    int s = blockIdx.x;
    int lane = threadIdx.x;
    int p = sorted[s];
    int e = ids[p];
    const unsigned short* ar = act + (size_t)s * HID;
    const float* da = down_a + (size_t)e * RANK * HID;
    float av[16];
#pragma unroll
    for (int i = 0; i < 16; ++i) av[i] = bf2f(ar[lane + i * 64]);
    for (int r = 0; r < RANK; ++r) {
        const float* a = da + (size_t)r * HID;
        float sum = 0.f;
#pragma unroll
        for (int i = 0; i < 16; ++i) sum += av[i] * a[lane + i * 64];
        for (int m = 32; m; m >>= 1) sum += __shfl_xor(sum, m, 64);
        if (lane == 0) t2[(size_t)s * RANK + r] = MOE_SCALE * sum;
    }
}

// ---------------------------------------------------------------------------
// Kernel: down-GEMM. Same structure; K=HID (16 kc), N-tile = 128 d rows.
// Epilogue: LoRA + topk-weight + atomic scatter-add.
// ---------------------------------------------------------------------------
__global__ __launch_bounds__(256) void k_down(
        const unsigned short* __restrict__ act, const unsigned short* __restrict__ pDn,
        const float* __restrict__ tw, const float* __restrict__ down_b,
        const float* __restrict__ t2,
        const int* __restrict__ offs, const int* __restrict__ sorted,
        float* __restrict__ out) {
    int e  = blockIdx.x >> 4;
    int mt = blockIdx.x & 15;
    int nt = blockIdx.y;
    int off = offs[e], cnt = offs[e + 1] - off;
    if (mt * 128 >= cnt) return;

    __shared__ unsigned short sA[128 * 64];
    __shared__ unsigned short sB[128 * 64];

    int tid = threadIdx.x, lane = tid & 63, wv = tid >> 6;
    int lm = lane & 15, lq = lane >> 4;

    int ar = tid >> 1;
    int acb = (tid & 1) * 4;
    const unsigned short* axp = nullptr;
    {
        int g = mt * 128 + ar;
        if (g < cnt) axp = act + (size_t)(off + g) * HID;
    }
    const unsigned short* bsrc = pDn + (size_t)(e * 16 + nt) * 16 * 8192;

    floatx4 acc[2][8];
    floatx4 zero = {0.f, 0.f, 0.f, 0.f};
#pragma unroll
    for (int i = 0; i < 2; ++i)
#pragma unroll
        for (int j = 0; j < 8; ++j) acc[i][j] = zero;

    for (int kc = 0; kc < 16; ++kc) {
        const unsigned short* bk = bsrc + kc * 8192;
#pragma unroll
        for (int j = 0; j < 4; ++j) {
            int ch = wv * 4 + j;
            gload16(bk + ch * 512 + lane * 8, (unsigned short*)sB + ch * 512);
        }
        if (axp) {
            const unsigned short* ap = axp + kc * 64;
#pragma unroll
            for (int i = 0; i < 4; ++i) {
                int c8 = acb + i;
                short8 v = *(const short8*)(ap + c8 * 8);
                *(short8*)(sA + ar * 64 + ((c8 ^ (ar & 7)) * 8)) = v;
            }
        }
        __syncthreads();
#pragma unroll
        for (int kk = 0; kk < 2; ++kk) {
            short8 af0, af1;
            {
                int r0 = (wv * 2) * 16 + lm;
                int r1 = (wv * 2 + 1) * 16 + lm;
                af0 = *(const short8*)(sA + r0 * 64 + (((kk * 4 + lq) ^ (r0 & 7)) * 8));
                af1 = *(const short8*)(sA + r1 * 64 + (((kk * 4 + lq) ^ (r1 & 7)) * 8));
            }
#pragma unroll
            for (int n2 = 0; n2 < 8; ++n2) {
                int r = n2 * 16 + lm;
                short8 bf = *(const short8*)(sB + r * 64 + (((kk * 4 + lq) ^ (r & 7)) * 8));
                acc[0][n2] = __builtin_amdgcn_mfma_f32_16x16x32_bf16(af0, bf, acc[0][n2], 0, 0, 0);
                acc[1][n2] = __builtin_amdgcn_mfma_f32_16x16x32_bf16(af1, bf, acc[1][n2], 0, 0, 0);
            }
        }
        __syncthreads();
    }

#pragma unroll
    for (int n2 = 0; n2 < 8; ++n2) {
        int d = nt * 128 + n2 * 16 + lm;
        const float* rb = down_b + ((size_t)e * DIM + d) * RANK;
        float rbv[RANK];
#pragma unroll
        for (int i = 0; i < RANK; ++i) rbv[i] = rb[i];
#pragma unroll
        for (int i = 0; i < 2; ++i) {
#pragma unroll
            for (int r = 0; r < 4; ++r) {
                int g = mt * 128 + (wv * 2 + i) * 16 + lq * 4 + r;
                if (g < cnt) {
                    int slot = off + g;
                    int p = sorted[slot];
                    const float* tv = t2 + (size_t)slot * RANK;
                    float val = acc[i][n2][r];
#pragma unroll
                    for (int j = 0; j < RANK; ++j) val += tv[j] * rbv[j];
                    atomicAdd(&out[(size_t)(p >> 1) * DIM + d], val * tw[p]);
                }
            }
        }
    }
}

// ---------------------------------------------------------------------------
extern "C" void kernel_launch(void* const* d_in, const int* in_sizes, int n_in,
                              void* d_out, int out_size, void* d_ws, size_t ws_size,
                              hipStream_t stream) {
    const float* x      = (const float*)d_in[0];
    const float* tw     = (const float*)d_in[1];
    const int*   ids    = (const int*)d_in[2];
    const float* w_up   = (const float*)d_in[3];
    const float* w_down = (const float*)d_in[4];
    const float* up_a   = (const float*)d_in[5];
    const float* up_b   = (const float*)d_in[6];
    const float* down_a = (const float*)d_in[7];
    const float* down_b = (const float*)d_in[8];
    float* out = (float*)d_out;

    char* ws = (char*)d_ws;
    int*   offs   = (int*)ws;                               // 68 B
    int*   sorted = (int*)(ws + 4096);                      // 8 KB
    float* t_up   = (float*)(ws + 16384);                   // 128 KB
    float* t2     = (float*)(ws + 163840);                  // 128 KB
    unsigned short* act = (unsigned short*)(ws + 524288);   // 4 MB
    unsigned short* xs  = (unsigned short*)(ws + 8388608);  // 8 MB
    unsigned short* pUp = (unsigned short*)(ws + 16777216); // 128 MB
    unsigned short* pDn = (unsigned short*)(ws + 16777216); // reuse (after k_up)

    hipMemsetAsync(d_out, 0, (size_t)out_size * sizeof(float), stream);

    k_routing<<<1, 256, 0, stream>>>(ids, offs, sorted);
    k_xspack<<<NPAIR, 256, 0, stream>>>(x, sorted, xs);
    k_tup<<<NPAIR, 64, 0, stream>>>(x, ids, up_a, t_up);
    k_packup<<<8192, 256, 0, stream>>>(w_up, pUp);

    dim3 gup(NEXP * 16, 16);
    k_up<<<gup, 256, 0, stream>>>(xs, pUp, up_b, t_up, offs, sorted, act);

    k_t2<<<NPAIR, 64, 0, stream>>>(act, ids, sorted, down_a, t2);
    k_packdn<<<4096, 256, 0, stream>>>(w_down, pDn);

    dim3 gdn(NEXP * 16, 16);
    k_down<<<gdn, 256, 0, stream>>>(act, pDn, tw, down_b, t2, offs, sorted, out);
}